// Round 1
// baseline (87.739 us; speedup 1.0000x reference)
//
#include <hip/hip_runtime.h>

#define NS 31      // N_STIM + 1
#define ND 10
#define BETA 10.0f

// One thread handles 4 rows -> all global accesses are 16B-aligned vectors.
// Pair table (q,r) -> (s0, s1) built once per block in LDS: removes all
// sqrt/exp/dot-product work from the per-row path.
__global__ __launch_bounds__(256) void rank_kernel(
    const int*   __restrict__ stim,   // (B,5) int32
    const float* __restrict__ gate,   // (B,2) f32
    const float* __restrict__ emb,    // (31,10) f32
    const float* __restrict__ w0,     // (10,) f32
    const float* __restrict__ w1,     // (10,) f32
    float*       __restrict__ out,    // (B,4) f32
    int B)
{
    __shared__ float2 st[NS * NS];

    // ---- build the 961-entry pair table (~4 pairs/thread) ----
    for (int p = threadIdx.x; p < NS * NS; p += 256) {
        int q = p / NS, r = p - q * NS;
        float a0 = 0.f, a1 = 0.f;
        #pragma unroll
        for (int d = 0; d < ND; ++d) {
            float diff = emb[q * ND + d] - emb[r * ND + d];
            float sq = diff * diff;
            a0 = fmaf(sq, w0[d], a0);
            a1 = fmaf(sq, w1[d], a1);
        }
        st[p] = make_float2(__expf(-BETA * sqrtf(a0)),
                            __expf(-BETA * sqrtf(a1)));
    }
    __syncthreads();

    long t  = (long)blockIdx.x * blockDim.x + threadIdx.x;
    long b0 = t * 4;
    if (b0 >= B) return;

    if (b0 + 4 <= B) {
        // vector fast path: 20 ints = 5 x int4 (aligned: b0*5*4 = 80*t bytes)
        const int4* sp = reinterpret_cast<const int4*>(stim + b0 * 5);
        int4 v0 = sp[0], v1 = sp[1], v2 = sp[2], v3 = sp[3], v4 = sp[4];
        const float4* gp = reinterpret_cast<const float4*>(gate + b0 * 2);
        float4 g01 = gp[0], g23 = gp[1];

        const int idx[4][5] = {
            {v0.x, v0.y, v0.z, v0.w, v1.x},
            {v1.y, v1.z, v1.w, v2.x, v2.y},
            {v2.z, v2.w, v3.x, v3.y, v3.z},
            {v3.w, v4.x, v4.y, v4.z, v4.w}
        };
        const float gx[4] = {g01.x, g01.z, g23.x, g23.z};
        const float gy[4] = {g01.y, g01.w, g23.y, g23.w};

        float4* op = reinterpret_cast<float4*>(out + b0 * 4);
        #pragma unroll
        for (int rw = 0; rw < 4; ++rw) {
            int qb = idx[rw][0] * NS;
            float s[4], sum = 0.f;
            #pragma unroll
            for (int i = 0; i < 4; ++i) {
                float2 sv = st[qb + idx[rw][i + 1]];
                float v = fmaf(gx[rw], sv.x, gy[rw] * sv.y);
                s[i] = v;
                sum += v;
            }
            float inv = 1.0f / sum;
            op[rw] = make_float4(s[0] * inv, s[1] * inv, s[2] * inv, s[3] * inv);
        }
    } else {
        // scalar tail (only if B % 4 != 0)
        for (long b = b0; b < B; ++b) {
            int q = stim[b * 5];
            float gxx = gate[b * 2], gyy = gate[b * 2 + 1];
            float s[4], sum = 0.f;
            #pragma unroll
            for (int i = 0; i < 4; ++i) {
                float2 sv = st[q * NS + stim[b * 5 + 1 + i]];
                float v = fmaf(gxx, sv.x, gyy * sv.y);
                s[i] = v;
                sum += v;
            }
            float inv = 1.0f / sum;
            #pragma unroll
            for (int i = 0; i < 4; ++i) out[b * 4 + i] = s[i] * inv;
        }
    }
}

extern "C" void kernel_launch(void* const* d_in, const int* in_sizes, int n_in,
                              void* d_out, int out_size, void* d_ws, size_t ws_size,
                              hipStream_t stream) {
    const int*   stim = (const int*)  d_in[0];
    const float* gate = (const float*)d_in[1];
    const float* emb  = (const float*)d_in[2];
    const float* w0   = (const float*)d_in[3];
    const float* w1   = (const float*)d_in[4];
    float* out = (float*)d_out;

    int B = in_sizes[0] / 5;                 // rows
    int rows_per_block = 256 * 4;
    int grid = (B + rows_per_block - 1) / rows_per_block;
    rank_kernel<<<grid, 256, 0, stream>>>(stim, gate, emb, w0, w1, out, B);
}